// Round 5
// baseline (159.215 us; speedup 1.0000x reference)
//
#include <hip/hip_runtime.h>

#define HID   384
#define K_PE  768     // 3*16*16
#define IMGST 150528  // 3*224*224 floats per image
#define POS   196

typedef unsigned short ushort_t;
using f32x4  = __attribute__((ext_vector_type(4))) float;
using short8 = __attribute__((ext_vector_type(8))) short;

// ---- bf16 helpers ----------------------------------------------------------
__device__ __forceinline__ unsigned bfpack(float lo, float hi) {   // RNE (prep)
    union { float f; unsigned u; } a, b; a.f = lo; b.f = hi;
    unsigned ra = (a.u + 0x7fffu + ((a.u >> 16) & 1u)) >> 16;
    unsigned rb = (b.u + 0x7fffu + ((b.u >> 16) & 1u)) & 0xffff0000u;
    return ra | rb;
}
__device__ __forceinline__ unsigned cvtpk(float lo, float hi) {    // RNE, 1 instr
    unsigned r;
    asm("v_cvt_pk_bf16_f32 %0, %1, %2" : "=v"(r) : "v"(lo), "v"(hi));
    return r;
}
union S8u { unsigned u[4]; short8 s; };

// ---------------- prep: zero scalars + swizzle W into B-frag order ----------
// Wfrag: [nt(24)][kc(24)][lane(64)][8] bf16; B-frag n = nt*16 + (lane&15),
// k = kc*32 + (lane>>4)*8 + j. grid 144 x 256 = 384 rows x 96 k-octets.
__global__ __launch_bounds__(256) void prep(const float* __restrict__ W,
                                            ushort_t* __restrict__ Wfrag,
                                            float* __restrict__ scal) {
    const int t = blockIdx.x * 256 + threadIdx.x;
    if (t < 4) scal[t] = 0.f;                  // T, S, pad, done-counter
    const int n  = t / 96;                     // 0..383
    const int ko = t - n * 96;                 // k-octet
    const float4 a  = *(const float4*)(W + (size_t)n * K_PE + ko * 8);
    const float4 bb = *(const float4*)(W + (size_t)n * K_PE + ko * 8 + 4);
    uint4 pq;
    pq.x = bfpack(a.x, a.y);   pq.y = bfpack(a.z, a.w);
    pq.z = bfpack(bb.x, bb.y); pq.w = bfpack(bb.z, bb.w);
    const int nt    = n >> 4;
    const int kc    = ko >> 2;
    const int lanew = (ko & 3) * 16 + (n & 15);
    ((uint4*)Wfrag)[(nt * 24 + kc) * 64 + lanew] = pq;
}

// ---------------- fused im2col + GEMM + softmax, BARRIER-FREE K-loop ---------
// grid 448 = 14 pi x 32 img-pairs. block 256 = 4 n-waves (96 cols each).
// M = 32 rows/tensor = 2 imgs x 14 pj (+4 pad dup of row 27). 24 K-steps of
// (c, kh-pair), K=32 each. Each lane loads its OWN A-frag directly from
// global (16-B contiguous: row pj*16+q*8 within an 896-B image row; the
// wave's 64 lanes exactly tile two rows -> fully coalesced). NO LDS, NO
// __syncthreads, NO vmcnt drain in the loop: waves free-run, A-floats and
// B-frags register-double-buffered one step ahead. A re-read 4x across
// waves hits L1/L2 (7-KB step window).
__global__ __launch_bounds__(256, 2) void pef(
    const float* __restrict__ x, const float* __restrict__ y,
    const ushort_t* __restrict__ Wfrag, const float* __restrict__ bias,
    float* __restrict__ scal, float* __restrict__ Lg, float* __restrict__ Qg) {
    const int blk = blockIdx.x;        // 0..447
    const int pi  = blk >> 5;          // 0..13
    const int ig  = blk & 31;          // img pair (imgs ig*2, ig*2+1)

    __shared__ float Smx[4][32], Ssx[4][32], Smy[4][32], Ssy[4][32];
    __shared__ float sT[4];

    const int tid  = threadIdx.x;
    const int wave = tid >> 6;         // n-wave: cols wave*96..+96
    const int lane = tid & 63;
    const int lm   = lane & 15;
    const int lq   = lane >> 4;

    // ---- per-lane A-frag base pointers: f = t*2 + mi
    // m = mi*16+lm (clamp 27) -> (img,pj); k-octet = lq -> khl=lq>>1, q=lq&1
    const float* sp[4];
#pragma unroll
    for (int f = 0; f < 4; ++f) {
        const int t = f >> 1, mi = f & 1;
        int m = mi * 16 + lm; if (m > 27) m = 27;   // pad rows dup row 27
        const int img = (m >= 14) ? 1 : 0;
        const int pj  = m - img * 14;
        sp[f] = (t ? y : x) + (size_t)(ig * 2 + img) * IMGST
              + (pi * 16 + (lq >> 1)) * 224 + pj * 16 + (lq & 1) * 8;
    }

    f32x4 accx[2][6] = {};
    f32x4 accy[2][6] = {};

    // step kn covers k in [kn*32, kn*32+32): c = kn>>3, kh-pair = kn&7
#define LOADA(F, KN)                                                          \
    {                                                                         \
        const int off_ = ((KN) >> 3) * 50176 + ((KN) & 7) * 448;              \
        _Pragma("unroll")                                                     \
        for (int f = 0; f < 4; ++f) {                                         \
            F[2 * f]     = *(const float4*)(sp[f] + off_);                    \
            F[2 * f + 1] = *(const float4*)(sp[f] + off_ + 4);                \
        }                                                                     \
    }
#define LOADB(B, KN)                                                          \
    {                                                                         \
        _Pragma("unroll")                                                     \
        for (int ni = 0; ni < 6; ++ni)                                        \
            B[ni] = *(const short8*)(Wfrag +                                  \
                    ((size_t)((wave * 6 + ni) * 24 + (KN)) * 64 + lane) * 8); \
    }
#define STEP(F, B)                                                            \
    {                                                                         \
        short8 af[4];                                                         \
        _Pragma("unroll")                                                     \
        for (int f = 0; f < 4; ++f) {                                         \
            S8u u_;                                                           \
            u_.u[0] = cvtpk(F[2 * f].x, F[2 * f].y);                          \
            u_.u[1] = cvtpk(F[2 * f].z, F[2 * f].w);                          \
            u_.u[2] = cvtpk(F[2 * f + 1].x, F[2 * f + 1].y);                  \
            u_.u[3] = cvtpk(F[2 * f + 1].z, F[2 * f + 1].w);                  \
            af[f] = u_.s;                                                     \
        }                                                                     \
        _Pragma("unroll")                                                     \
        for (int mi = 0; mi < 2; ++mi)                                        \
            _Pragma("unroll")                                                 \
            for (int ni = 0; ni < 6; ++ni) {                                  \
                accx[mi][ni] = __builtin_amdgcn_mfma_f32_16x16x32_bf16(       \
                    af[mi], B[ni], accx[mi][ni], 0, 0, 0);                    \
                accy[mi][ni] = __builtin_amdgcn_mfma_f32_16x16x32_bf16(       \
                    af[2 + mi], B[ni], accy[mi][ni], 0, 0, 0);                \
            }                                                                 \
    }

    float4 fA[8], fB[8];
    short8 bA[6], bB[6];
    LOADA(fA, 0) LOADB(bA, 0)
    for (int kk2 = 0; kk2 < 12; ++kk2) {
        const int k1 = kk2 * 2 + 1;
        const int k2 = (k1 < 23) ? k1 + 1 : 0;   // dummy wrap on last iter
        LOADA(fB, k1) LOADB(bB, k1)
        STEP(fA, bA)
        LOADA(fA, k2) LOADB(bA, k2)
        STEP(fB, bB)
    }
#undef LOADA
#undef LOADB
#undef STEP

    // ---- epilogue: D col = wave*96 + ni*16 + lm; row = mi*16 + lq*4 + r
#pragma unroll
    for (int ni = 0; ni < 6; ++ni) {
        const float bv = bias[wave * 96 + ni * 16 + lm];
#pragma unroll
        for (int mi = 0; mi < 2; ++mi)
#pragma unroll
            for (int r = 0; r < 4; ++r) {
                accx[mi][ni][r] += bv;
                accy[mi][ni][r] += bv;
            }
    }

    float mx[2][4], my_[2][4];
#pragma unroll
    for (int mi = 0; mi < 2; ++mi)
#pragma unroll
        for (int r = 0; r < 4; ++r) {
            float a = accx[mi][0][r], bb = accy[mi][0][r];
#pragma unroll
            for (int ni = 1; ni < 6; ++ni) {
                a  = fmaxf(a,  accx[mi][ni][r]);
                bb = fmaxf(bb, accy[mi][ni][r]);
            }
            mx[mi][r] = a; my_[mi][r] = bb;
        }
#pragma unroll
    for (int off = 1; off < 16; off <<= 1)
#pragma unroll
        for (int mi = 0; mi < 2; ++mi)
#pragma unroll
            for (int r = 0; r < 4; ++r) {
                mx[mi][r]  = fmaxf(mx[mi][r],  __shfl_xor(mx[mi][r],  off));
                my_[mi][r] = fmaxf(my_[mi][r], __shfl_xor(my_[mi][r], off));
            }
    if (lm == 0)
#pragma unroll
        for (int mi = 0; mi < 2; ++mi)
#pragma unroll
            for (int r = 0; r < 4; ++r) {
                Smx[wave][mi * 16 + lq * 4 + r] = mx[mi][r];
                Smy[wave][mi * 16 + lq * 4 + r] = my_[mi][r];
            }
    __syncthreads();
#pragma unroll
    for (int mi = 0; mi < 2; ++mi)
#pragma unroll
        for (int r = 0; r < 4; ++r) {
            const int row = mi * 16 + lq * 4 + r;
            mx[mi][r]  = fmaxf(fmaxf(Smx[0][row], Smx[1][row]),
                               fmaxf(Smx[2][row], Smx[3][row]));
            my_[mi][r] = fmaxf(fmaxf(Smy[0][row], Smy[1][row]),
                               fmaxf(Smy[2][row], Smy[3][row]));
        }

    float sx[2][4], sy[2][4];
#pragma unroll
    for (int mi = 0; mi < 2; ++mi)
#pragma unroll
        for (int r = 0; r < 4; ++r) {
            float a = 0.f, bb = 0.f;
#pragma unroll
            for (int ni = 0; ni < 6; ++ni) {
                a  += __expf(accx[mi][ni][r] - mx[mi][r]);
                bb += __expf(accy[mi][ni][r] - my_[mi][r]);
            }
            sx[mi][r] = a; sy[mi][r] = bb;
        }
#pragma unroll
    for (int off = 1; off < 16; off <<= 1)
#pragma unroll
        for (int mi = 0; mi < 2; ++mi)
#pragma unroll
            for (int r = 0; r < 4; ++r) {
                sx[mi][r] += __shfl_xor(sx[mi][r], off);
                sy[mi][r] += __shfl_xor(sy[mi][r], off);
            }
    if (lm == 0)
#pragma unroll
        for (int mi = 0; mi < 2; ++mi)
#pragma unroll
            for (int r = 0; r < 4; ++r) {
                Ssx[wave][mi * 16 + lq * 4 + r] = sx[mi][r];
                Ssy[wave][mi * 16 + lq * 4 + r] = sy[mi][r];
            }
    __syncthreads();
    float shx[2][4], invy[2][4];
#pragma unroll
    for (int mi = 0; mi < 2; ++mi)
#pragma unroll
        for (int r = 0; r < 4; ++r) {
            const int row = mi * 16 + lq * 4 + r;
            const float ssx = Ssx[0][row] + Ssx[1][row] + Ssx[2][row] + Ssx[3][row];
            const float ssy = Ssy[0][row] + Ssy[1][row] + Ssy[2][row] + Ssy[3][row];
            shx[mi][r]  = mx[mi][r] + __logf(ssx);   // logp shift
            invy[mi][r] = 1.f / ssy;                 // q scale
        }

    // ---- T partial + per-element logp/q stores (valid rows m < 28 only)
    float T = 0.f;
#pragma unroll
    for (int mi = 0; mi < 2; ++mi)
#pragma unroll
        for (int r = 0; r < 4; ++r) {
            const int m = mi * 16 + lq * 4 + r;
            if (m < 28) {
                const int img = (m >= 14) ? 1 : 0;
                const int pj  = m - img * 14;
                const size_t lb = ((size_t)(pi * 64 + ig * 2 + img) * 14 + pj) * 384
                                  + wave * 96 + lm;
                const float sh  = shx[mi][r];
                const float mm  = my_[mi][r];
                const float inv = invy[mi][r];
#pragma unroll
                for (int ni = 0; ni < 6; ++ni) {
                    const float lp = accx[mi][ni][r] - sh;
                    const float qv = __expf(accy[mi][ni][r] - mm) * inv;
                    T += lp * qv;
                    Lg[lb + ni * 16] = lp;
                    Qg[lb + ni * 16] = qv;
                }
            }
        }
#pragma unroll
    for (int off = 32; off > 0; off >>= 1) T += __shfl_xor(T, off);
    if (lane == 0) sT[wave] = T;
    __syncthreads();
    if (tid == 0) atomicAdd(&scal[0], sT[0] + sT[1] + sT[2] + sT[3]);
}

// ---------------- fin: per-position L/Q col sums -> S; final scalar ---------
// grid 196 (one block per position), block 768: (img-half h, col c).
__global__ __launch_bounds__(768) void fin(const float* __restrict__ Lg,
                                           const float* __restrict__ Qg,
                                           float* __restrict__ scal,
                                           float* __restrict__ out) {
    const int p  = blockIdx.x;
    const int pi = p / 14;
    const int pj = p - pi * 14;
    const int t  = threadIdx.x;
    const int h  = t / 384;                    // img half
    const int c  = t - h * 384;                // 0..383
    float L = 0.f, Q = 0.f;
#pragma unroll 4
    for (int i = 0; i < 32; ++i) {
        const int img = h * 32 + i;
        const size_t o = ((size_t)(pi * 64 + img) * 14 + pj) * 384 + c;
        L += Lg[o];
        Q += Qg[o];
    }
    __shared__ float LL[384], QQ[384];
    if (h == 0) { LL[c] = L; QQ[c] = Q; }
    __syncthreads();
    float s = 0.f;
    if (h == 1) s = (LL[c] + L) * (QQ[c] + Q);
#pragma unroll
    for (int off = 32; off > 0; off >>= 1) s += __shfl_xor(s, off);
    __shared__ float sw[12];
    if ((t & 63) == 0) sw[t >> 6] = s;
    __syncthreads();
    if (t == 0) {
        float Sp = 0.f;
#pragma unroll
        for (int w = 0; w < 12; ++w) Sp += sw[w];
        atomicAdd(&scal[1], Sp);
        __threadfence();
        const int old = atomicAdd((int*)&scal[3], 1);
        if (old == POS - 1) {
            const float T = atomicAdd(&scal[0], 0.f);   // coherent read-back
            const float S = atomicAdd(&scal[1], 0.f);
            out[0] = 63.f * T / (S - T);
        }
    }
}

extern "C" void kernel_launch(void* const* d_in, const int* in_sizes, int n_in,
                              void* d_out, int out_size, void* d_ws, size_t ws_size,
                              hipStream_t stream) {
    const float* x = (const float*)d_in[0];   // (64,3,224,224)
    const float* y = (const float*)d_in[1];   // (64,3,224,224)
    const float* W = (const float*)d_in[2];   // (384,768)
    const float* b = (const float*)d_in[3];   // (384,)
    float* out = (float*)d_out;

    char* ws = (char*)d_ws;
    float*    scal  = (float*)ws;                      // 64 B (pad to 1 KB)
    ushort_t* Wfrag = (ushort_t*)(ws + 1024);          // 589,824 B
    float*    Lg    = (float*)(ws + 590848);           // 19,267,584 B
    float*    Qg    = (float*)(ws + 19858432);         // 19,267,584 B

    prep<<<144, 256, 0, stream>>>(W, Wfrag, scal);
    pef<<<448, 256, 0, stream>>>(x, y, Wfrag, b, scal, Lg, Qg);
    fin<<<196, 768, 0, stream>>>(Lg, Qg, scal, out);
}

// Round 6
// 136.567 us; speedup vs baseline: 1.1658x; 1.1658x over previous
//
#include <hip/hip_runtime.h>

#define HID   384
#define K_PE  768     // 3*16*16
#define IMGST 150528  // 3*224*224 floats per image
#define POS   196

typedef unsigned short ushort_t;
using f32x4  = __attribute__((ext_vector_type(4))) float;
using short8 = __attribute__((ext_vector_type(8))) short;

// ---- bf16 helpers ----------------------------------------------------------
__device__ __forceinline__ unsigned bfpack(float lo, float hi) {   // RNE (prep)
    union { float f; unsigned u; } a, b; a.f = lo; b.f = hi;
    unsigned ra = (a.u + 0x7fffu + ((a.u >> 16) & 1u)) >> 16;
    unsigned rb = (b.u + 0x7fffu + ((b.u >> 16) & 1u)) & 0xffff0000u;
    return ra | rb;
}
__device__ __forceinline__ unsigned cvtpk(float lo, float hi) {    // RNE, 1 instr
    unsigned r;
    asm("v_cvt_pk_bf16_f32 %0, %1, %2" : "=v"(r) : "v"(lo), "v"(hi));
    return r;
}
__device__ __forceinline__ float bf2f(unsigned hibits) {
    union { unsigned u; float f; } v; v.u = hibits; return v.f;
}

// ---------------- prep: zero scalars + swizzle W into B-frag order ----------
// Wfrag: [nt(24)][kc(24)][lane(64)][8] bf16; B-frag n = nt*16 + (lane&15),
// k = kc*32 + (lane>>4)*8 + j. grid 144 x 256 = 384 rows x 96 k-octets.
__global__ __launch_bounds__(256) void prep(const float* __restrict__ W,
                                            ushort_t* __restrict__ Wfrag,
                                            float* __restrict__ scal) {
    const int t = blockIdx.x * 256 + threadIdx.x;
    if (t < 4) scal[t] = 0.f;                  // T, S, pad, done-counter
    const int n  = t / 96;                     // 0..383
    const int ko = t - n * 96;                 // k-octet
    const float4 a  = *(const float4*)(W + (size_t)n * K_PE + ko * 8);
    const float4 bb = *(const float4*)(W + (size_t)n * K_PE + ko * 8 + 4);
    uint4 pq;
    pq.x = bfpack(a.x, a.y);   pq.y = bfpack(a.z, a.w);
    pq.z = bfpack(bb.x, bb.y); pq.w = bfpack(bb.z, bb.w);
    const int nt    = n >> 4;
    const int kc    = ko >> 2;
    const int lanew = (ko & 3) * 16 + (n & 15);
    ((uint4*)Wfrag)[(nt * 24 + kc) * 64 + lanew] = pq;
}

// ---------------- fused im2col + GEMM + softmax ------------------------------
// grid 448 = 14 pi x 32 img-pairs. block 256 = 4 n-waves (96 cols each).
// M = 32 rows/tensor = 2 imgs x 14 pj (+4 pad dup of row 27).
// K-loop: 12 steps of K=64 (channel c = kk>>2, kh-quad = kk&3). Per step the
// block reads 16 contiguous 896-B HBM rows, packs bf16 into LDS (o-stride
// padded to 912 B -> bank phases rotate, kills R4's 1M conflicts). 48
// MFMA/wave/step hides B-L2 + stage latency; B-frags register-rotated one
// ks ahead; 12 barriers total (was 24). Epilogue: fused softmax; T (fp32) ->
// atomicAdd; (logp, q) packed to ONE bf16x2 word -> Zg[p][img][c]
// (halves intermediate EA traffic vs f32 pairs).
__global__ __launch_bounds__(256, 2) void pef(
    const float* __restrict__ x, const float* __restrict__ y,
    const ushort_t* __restrict__ Wfrag, const float* __restrict__ bias,
    float* __restrict__ scal, unsigned* __restrict__ Zg) {
    const int blk = blockIdx.x;        // 0..447
    const int pi  = blk >> 5;          // 0..13
    const int ig  = blk & 31;          // img pair (imgs ig*2, ig*2+1)

    // As: [buf][o(8) @456 ush][t(2)][img(2)][pj(14)][8 ush]; 912 B per octet
    __shared__ __align__(16) ushort_t As[2][8 * 456];
    __shared__ float Smx[4][32], Ssx[4][32], Smy[4][32], Ssy[4][32];
    __shared__ float sT[4];

    const int tid  = threadIdx.x;
    const int wave = tid >> 6;         // n-wave: cols wave*96..+96
    const int lane = tid & 63;
    const int lm   = lane & 15;
    const int lq   = lane >> 4;

    // ---- staging ids: rr = (t, img, kh&1); sj = (pj, q); each thread loads
    // rows kh_local = skh and skh+2 of the current kh-quad.
    const int rr   = tid >> 5;         // 0..7
    const int sj   = tid & 31;         // active < 28
    const int st   = rr >> 2;
    const int simg = (rr >> 1) & 1;
    const int skh  = rr & 1;
    const int sq   = sj & 1;
    const int spj  = sj >> 1;
    const bool sact = sj < 28;
    const float* srow = (st ? y : x) +
        (size_t)(ig * 2 + simg) * IMGST + pi * 3584 + skh * 224 + sj * 8;
    const int ainner = st * 224 + simg * 112 + spj * 8;
    const int aoff0  = (skh * 2 + sq) * 456 + ainner;          // kh_local = skh
    const int aoff1  = ((skh + 2) * 2 + sq) * 456 + ainner;    // kh_local = skh+2

    // ---- A-frag read offsets: m = mi*16+lm (clamp 27) -> (img,pj)
    int ard[2][2];   // [t][mi], add (ks*4+lq)*456 for the octet
#pragma unroll
    for (int t = 0; t < 2; ++t)
#pragma unroll
        for (int mi = 0; mi < 2; ++mi) {
            int m = mi * 16 + lm; if (m > 27) m = 27;   // pad rows dup row 27
            const int img = (m >= 14) ? 1 : 0;
            const int pj  = m - img * 14;
            ard[t][mi] = t * 224 + img * 112 + pj * 8;
        }
    const int ob0 = lq * 456, ob1 = (4 + lq) * 456;

    f32x4 accx[2][6] = {};
    f32x4 accy[2][6] = {};

#define LOADB(B, KC)                                                          \
    {                                                                         \
        _Pragma("unroll")                                                     \
        for (int ni = 0; ni < 6; ++ni)                                        \
            B[ni] = *(const short8*)(Wfrag +                                  \
                    ((size_t)((wave * 6 + ni) * 24 + (KC)) * 64 + lane) * 8); \
    }
#define MFMA24(AF, B, ACX, ACY)                                               \
    {                                                                         \
        _Pragma("unroll")                                                     \
        for (int mi = 0; mi < 2; ++mi)                                        \
            _Pragma("unroll")                                                 \
            for (int ni = 0; ni < 6; ++ni) {                                  \
                ACX[mi][ni] = __builtin_amdgcn_mfma_f32_16x16x32_bf16(        \
                    AF[0][mi], B[ni], ACX[mi][ni], 0, 0, 0);                  \
                ACY[mi][ni] = __builtin_amdgcn_mfma_f32_16x16x32_bf16(        \
                    AF[1][mi], B[ni], ACY[mi][ni], 0, 0, 0);                  \
            }                                                                 \
    }

    // ---- prologue: stage step 0 directly, preload B(kk=0, ks=0)
    if (sact) {
        const float4 f0 = *(const float4*)(srow);
        const float4 f1 = *(const float4*)(srow + 4);
        const float4 f2 = *(const float4*)(srow + 448);   // kh_local+2
        const float4 f3 = *(const float4*)(srow + 452);
        uint4 p0, p1;
        p0.x = bfpack(f0.x, f0.y); p0.y = bfpack(f0.z, f0.w);
        p0.z = bfpack(f1.x, f1.y); p0.w = bfpack(f1.z, f1.w);
        p1.x = bfpack(f2.x, f2.y); p1.y = bfpack(f2.z, f2.w);
        p1.z = bfpack(f3.x, f3.y); p1.w = bfpack(f3.z, f3.w);
        *(uint4*)&As[0][aoff0] = p0;
        *(uint4*)&As[0][aoff1] = p1;
    }
    short8 b0[6], b1[6], bn[6];
    LOADB(b0, 0)
    __syncthreads();

#pragma unroll 2
    for (int kk = 0; kk < 12; ++kk) {
        const int cur = kk & 1;
        const bool have = sact && (kk < 11);
        // T14 issue-early: next step's 16 rows (consumed after the MFMAs)
        const int nb = ((kk + 1) >> 2) * 50176 + ((kk + 1) & 3) * 896;
        float4 f0{}, f1{}, f2{}, f3{};
        if (have) {
            f0 = *(const float4*)(srow + nb);
            f1 = *(const float4*)(srow + nb + 4);
            f2 = *(const float4*)(srow + nb + 448);
            f3 = *(const float4*)(srow + nb + 452);
        }
        LOADB(b1, kk * 2 + 1)                 // ks=1 B-frags (hidden by ks0 MFMAs)
        short8 af[2][2];
#pragma unroll
        for (int t = 0; t < 2; ++t)
#pragma unroll
            for (int mi = 0; mi < 2; ++mi)
                af[t][mi] = *(const short8*)&As[cur][ob0 + ard[t][mi]];
        MFMA24(af, b0, accx, accy)
        const int kn2 = (kk < 11) ? (kk + 1) * 2 : 0;
        LOADB(bn, kn2)                        // next step ks=0 (hidden by ks1)
#pragma unroll
        for (int t = 0; t < 2; ++t)
#pragma unroll
            for (int mi = 0; mi < 2; ++mi)
                af[t][mi] = *(const short8*)&As[cur][ob1 + ard[t][mi]];
        MFMA24(af, b1, accx, accy)
        // write-late: vmcnt for f0..f3 + pack + LDS store after the MFMAs
        if (have) {
            uint4 p0, p1;
            p0.x = bfpack(f0.x, f0.y); p0.y = bfpack(f0.z, f0.w);
            p0.z = bfpack(f1.x, f1.y); p0.w = bfpack(f1.z, f1.w);
            p1.x = bfpack(f2.x, f2.y); p1.y = bfpack(f2.z, f2.w);
            p1.z = bfpack(f3.x, f3.y); p1.w = bfpack(f3.z, f3.w);
            *(uint4*)&As[cur ^ 1][aoff0] = p0;
            *(uint4*)&As[cur ^ 1][aoff1] = p1;
        }
#pragma unroll
        for (int ni = 0; ni < 6; ++ni) b0[ni] = bn[ni];
        __syncthreads();
    }
#undef LOADB
#undef MFMA24

    // ---- epilogue: D col = wave*96 + ni*16 + lm; row = mi*16 + lq*4 + r
#pragma unroll
    for (int ni = 0; ni < 6; ++ni) {
        const float bv = bias[wave * 96 + ni * 16 + lm];
#pragma unroll
        for (int mi = 0; mi < 2; ++mi)
#pragma unroll
            for (int r = 0; r < 4; ++r) {
                accx[mi][ni][r] += bv;
                accy[mi][ni][r] += bv;
            }
    }

    float mx[2][4], my_[2][4];
#pragma unroll
    for (int mi = 0; mi < 2; ++mi)
#pragma unroll
        for (int r = 0; r < 4; ++r) {
            float a = accx[mi][0][r], bb = accy[mi][0][r];
#pragma unroll
            for (int ni = 1; ni < 6; ++ni) {
                a  = fmaxf(a,  accx[mi][ni][r]);
                bb = fmaxf(bb, accy[mi][ni][r]);
            }
            mx[mi][r] = a; my_[mi][r] = bb;
        }
#pragma unroll
    for (int off = 1; off < 16; off <<= 1)
#pragma unroll
        for (int mi = 0; mi < 2; ++mi)
#pragma unroll
            for (int r = 0; r < 4; ++r) {
                mx[mi][r]  = fmaxf(mx[mi][r],  __shfl_xor(mx[mi][r],  off));
                my_[mi][r] = fmaxf(my_[mi][r], __shfl_xor(my_[mi][r], off));
            }
    if (lm == 0)
#pragma unroll
        for (int mi = 0; mi < 2; ++mi)
#pragma unroll
            for (int r = 0; r < 4; ++r) {
                Smx[wave][mi * 16 + lq * 4 + r] = mx[mi][r];
                Smy[wave][mi * 16 + lq * 4 + r] = my_[mi][r];
            }
    __syncthreads();
#pragma unroll
    for (int mi = 0; mi < 2; ++mi)
#pragma unroll
        for (int r = 0; r < 4; ++r) {
            const int row = mi * 16 + lq * 4 + r;
            mx[mi][r]  = fmaxf(fmaxf(Smx[0][row], Smx[1][row]),
                               fmaxf(Smx[2][row], Smx[3][row]));
            my_[mi][r] = fmaxf(fmaxf(Smy[0][row], Smy[1][row]),
                               fmaxf(Smy[2][row], Smy[3][row]));
        }

    float sx[2][4], sy[2][4];
#pragma unroll
    for (int mi = 0; mi < 2; ++mi)
#pragma unroll
        for (int r = 0; r < 4; ++r) {
            float a = 0.f, bb = 0.f;
#pragma unroll
            for (int ni = 0; ni < 6; ++ni) {
                a  += __expf(accx[mi][ni][r] - mx[mi][r]);
                bb += __expf(accy[mi][ni][r] - my_[mi][r]);
            }
            sx[mi][r] = a; sy[mi][r] = bb;
        }
#pragma unroll
    for (int off = 1; off < 16; off <<= 1)
#pragma unroll
        for (int mi = 0; mi < 2; ++mi)
#pragma unroll
            for (int r = 0; r < 4; ++r) {
                sx[mi][r] += __shfl_xor(sx[mi][r], off);
                sy[mi][r] += __shfl_xor(sy[mi][r], off);
            }
    if (lm == 0)
#pragma unroll
        for (int mi = 0; mi < 2; ++mi)
#pragma unroll
            for (int r = 0; r < 4; ++r) {
                Ssx[wave][mi * 16 + lq * 4 + r] = sx[mi][r];
                Ssy[wave][mi * 16 + lq * 4 + r] = sy[mi][r];
            }
    __syncthreads();
    float shx[2][4], invy[2][4];
#pragma unroll
    for (int mi = 0; mi < 2; ++mi)
#pragma unroll
        for (int r = 0; r < 4; ++r) {
            const int row = mi * 16 + lq * 4 + r;
            const float ssx = Ssx[0][row] + Ssx[1][row] + Ssx[2][row] + Ssx[3][row];
            const float ssy = Ssy[0][row] + Ssy[1][row] + Ssy[2][row] + Ssy[3][row];
            shx[mi][r]  = mx[mi][r] + __logf(ssx);   // logp shift
            invy[mi][r] = 1.f / ssy;                 // q scale
        }

    // ---- T partial (fp32) + packed bf16x2 (logp,q) stores (rows m < 28)
    float T = 0.f;
#pragma unroll
    for (int mi = 0; mi < 2; ++mi)
#pragma unroll
        for (int r = 0; r < 4; ++r) {
            const int m = mi * 16 + lq * 4 + r;
            if (m < 28) {
                const int img = (m >= 14) ? 1 : 0;
                const int pj  = m - img * 14;
                const size_t lb = ((size_t)(pi * 14 + pj) * 64 + ig * 2 + img) * 384
                                  + wave * 96 + lm;
                const float sh  = shx[mi][r];
                const float mm  = my_[mi][r];
                const float inv = invy[mi][r];
#pragma unroll
                for (int ni = 0; ni < 6; ++ni) {
                    const float lp = accx[mi][ni][r] - sh;
                    const float qv = __expf(accy[mi][ni][r] - mm) * inv;
                    T += lp * qv;
                    Zg[lb + ni * 16] = cvtpk(lp, qv);   // bf16 lp | bf16 qv <<16
                }
            }
        }
#pragma unroll
    for (int off = 32; off > 0; off >>= 1) T += __shfl_xor(T, off);
    if (lane == 0) sT[wave] = T;
    __syncthreads();
    if (tid == 0) atomicAdd(&scal[0], sT[0] + sT[1] + sT[2] + sT[3]);
}

// ---------------- fin: per-position L/Q col sums -> S; final scalar ---------
// grid 196 (one block per position; Zg[p] is one contiguous 98 KB stream),
// block 768: (img-half h, col c).
__global__ __launch_bounds__(768) void fin(const unsigned* __restrict__ Zg,
                                           float* __restrict__ scal,
                                           float* __restrict__ out) {
    const int p = blockIdx.x;
    const int t = threadIdx.x;
    const int h = t / 384;                     // img half
    const int c = t - h * 384;                 // 0..383
    float L = 0.f, Q = 0.f;
#pragma unroll 4
    for (int i = 0; i < 32; ++i) {
        const unsigned u = Zg[((size_t)p * 64 + h * 32 + i) * 384 + c];
        L += bf2f(u << 16);
        Q += bf2f(u & 0xffff0000u);
    }
    __shared__ float LL[384], QQ[384];
    if (h == 0) { LL[c] = L; QQ[c] = Q; }
    __syncthreads();
    float s = 0.f;
    if (h == 1) s = (LL[c] + L) * (QQ[c] + Q);
#pragma unroll
    for (int off = 32; off > 0; off >>= 1) s += __shfl_xor(s, off);
    __shared__ float sw[12];
    if ((t & 63) == 0) sw[t >> 6] = s;
    __syncthreads();
    if (t == 0) {
        float Sp = 0.f;
#pragma unroll
        for (int w = 0; w < 12; ++w) Sp += sw[w];
        atomicAdd(&scal[1], Sp);
        __threadfence();
        const int old = atomicAdd((int*)&scal[3], 1);
        if (old == POS - 1) {
            const float T = atomicAdd(&scal[0], 0.f);   // coherent read-back
            const float S = atomicAdd(&scal[1], 0.f);
            out[0] = 63.f * T / (S - T);
        }
    }
}

extern "C" void kernel_launch(void* const* d_in, const int* in_sizes, int n_in,
                              void* d_out, int out_size, void* d_ws, size_t ws_size,
                              hipStream_t stream) {
    const float* x = (const float*)d_in[0];   // (64,3,224,224)
    const float* y = (const float*)d_in[1];   // (64,3,224,224)
    const float* W = (const float*)d_in[2];   // (384,768)
    const float* b = (const float*)d_in[3];   // (384,)
    float* out = (float*)d_out;

    char* ws = (char*)d_ws;
    float*    scal  = (float*)ws;                      // 64 B (pad to 1 KB)
    ushort_t* Wfrag = (ushort_t*)(ws + 1024);          // 589,824 B
    unsigned* Zg    = (unsigned*)(ws + 590848);        // 19,267,584 B

    prep<<<144, 256, 0, stream>>>(W, Wfrag, scal);
    pef<<<448, 256, 0, stream>>>(x, y, Wfrag, b, scal, Zg);
    fin<<<196, 768, 0, stream>>>(Zg, scal, out);
}

// Round 7
// 136.551 us; speedup vs baseline: 1.1660x; 1.0001x over previous
//
#include <hip/hip_runtime.h>

#define HID   384
#define K_PE  768     // 3*16*16
#define IMGST 150528  // 3*224*224 floats per image
#define POS   196

typedef unsigned short ushort_t;
using f32x4  = __attribute__((ext_vector_type(4))) float;
using short8 = __attribute__((ext_vector_type(8))) short;

// ---- bf16 helpers ----------------------------------------------------------
__device__ __forceinline__ unsigned bfpack(float lo, float hi) {   // RNE (prep)
    union { float f; unsigned u; } a, b; a.f = lo; b.f = hi;
    unsigned ra = (a.u + 0x7fffu + ((a.u >> 16) & 1u)) >> 16;
    unsigned rb = (b.u + 0x7fffu + ((b.u >> 16) & 1u)) & 0xffff0000u;
    return ra | rb;
}
__device__ __forceinline__ unsigned cvtpk(float lo, float hi) {    // RNE, 1 instr
    unsigned r;
    asm("v_cvt_pk_bf16_f32 %0, %1, %2" : "=v"(r) : "v"(lo), "v"(hi));
    return r;
}
__device__ __forceinline__ float bf2f(unsigned hibits) {
    union { unsigned u; float f; } v; v.u = hibits; return v.f;
}

// ---------------- prep: zero scalars + swizzle W into B-frag order ----------
// Wfrag: [nt(24)][kc(24)][lane(64)][8] bf16; B-frag n = nt*16 + (lane&15),
// k = kc*32 + (lane>>4)*8 + j. grid 144 x 256 = 384 rows x 96 k-octets.
__global__ __launch_bounds__(256) void prep(const float* __restrict__ W,
                                            ushort_t* __restrict__ Wfrag,
                                            float* __restrict__ scal) {
    const int t = blockIdx.x * 256 + threadIdx.x;
    if (t < 4) scal[t] = 0.f;                  // T, S, pad, done-counter
    const int n  = t / 96;                     // 0..383
    const int ko = t - n * 96;                 // k-octet
    const float4 a  = *(const float4*)(W + (size_t)n * K_PE + ko * 8);
    const float4 bb = *(const float4*)(W + (size_t)n * K_PE + ko * 8 + 4);
    uint4 pq;
    pq.x = bfpack(a.x, a.y);   pq.y = bfpack(a.z, a.w);
    pq.z = bfpack(bb.x, bb.y); pq.w = bfpack(bb.z, bb.w);
    const int nt    = n >> 4;
    const int kc    = ko >> 2;
    const int lanew = (ko & 3) * 16 + (n & 15);
    ((uint4*)Wfrag)[(nt * 24 + kc) * 64 + lanew] = pq;
}

// ---------------- fused im2col + GEMM + softmax ------------------------------
// grid 448 = 14 pi x 32 img-pairs. block 256 = 4 n-waves (96 cols each).
// M = 32 rows/tensor = 2 imgs x 14 pj (+4 pad dup of row 27).
// K-loop: 12 steps of K=64 (channel c = kk>>2, kh-quad = kk&3); per step the
// block reads 16 contiguous 896-B HBM rows, packs bf16 into LDS.
// R7: 3-DEEP register staging. pf[3] holds three pending steps' floats:
// iter kk issues step kk+3's loads into pf[kk%3] and retires step kk+1
// (pf[(kk+1)%3], issued 2 iters earlier -> ~2.8 step-times of latency slack)
// into LDS after the MFMAs. In-flight bytes/block triple (7->21 KB), the
// counted vmcnt is compiler-derived. #pragma unroll 6 (lcm of buf parity 2
// and set parity 3) keeps pf indices compile-time (no scratch).
// Epilogue: fused softmax; T (fp32) -> atomicAdd; (logp, q) packed to one
// bf16x2 word -> Zg[p][img][c].
__global__ __launch_bounds__(256, 2) void pef(
    const float* __restrict__ x, const float* __restrict__ y,
    const ushort_t* __restrict__ Wfrag, const float* __restrict__ bias,
    float* __restrict__ scal, unsigned* __restrict__ Zg) {
    const int blk = blockIdx.x;        // 0..447
    const int pi  = blk >> 5;          // 0..13
    const int ig  = blk & 31;          // img pair (imgs ig*2, ig*2+1)

    // As: [buf][o(8) @456 ush][t(2)][img(2)][pj(14)][8 ush]
    __shared__ __align__(16) ushort_t As[2][8 * 456];
    __shared__ float Smx[4][32], Ssx[4][32], Smy[4][32], Ssy[4][32];
    __shared__ float sT[4];

    const int tid  = threadIdx.x;
    const int wave = tid >> 6;         // n-wave: cols wave*96..+96
    const int lane = tid & 63;
    const int lm   = lane & 15;
    const int lq   = lane >> 4;

    // ---- staging ids: rr = (t, img, kh&1); sj = (pj, q); each thread loads
    // rows kh_local = skh and skh+2 of the current kh-quad.
    const int rr   = tid >> 5;         // 0..7
    const int sj   = tid & 31;         // active < 28
    const int st   = rr >> 2;
    const int simg = (rr >> 1) & 1;
    const int skh  = rr & 1;
    const int sq   = sj & 1;
    const int spj  = sj >> 1;
    const bool sact = sj < 28;
    const float* srow = (st ? y : x) +
        (size_t)(ig * 2 + simg) * IMGST + pi * 3584 + skh * 224 + sj * 8;
    const int ainner = st * 224 + simg * 112 + spj * 8;
    const int aoff0  = (skh * 2 + sq) * 456 + ainner;          // kh_local = skh
    const int aoff1  = ((skh + 2) * 2 + sq) * 456 + ainner;    // kh_local = skh+2

    // ---- A-frag read offsets: m = mi*16+lm (clamp 27) -> (img,pj)
    int ard[2][2];   // [t][mi], add octet*456
#pragma unroll
    for (int t = 0; t < 2; ++t)
#pragma unroll
        for (int mi = 0; mi < 2; ++mi) {
            int m = mi * 16 + lm; if (m > 27) m = 27;   // pad rows dup row 27
            const int img = (m >= 14) ? 1 : 0;
            const int pj  = m - img * 14;
            ard[t][mi] = t * 224 + img * 112 + pj * 8;
        }
    const int ob0 = lq * 456, ob1 = (4 + lq) * 456;

    f32x4 accx[2][6] = {};
    f32x4 accy[2][6] = {};

#define LOADB(B, KC)                                                          \
    {                                                                         \
        _Pragma("unroll")                                                     \
        for (int ni = 0; ni < 6; ++ni)                                        \
            B[ni] = *(const short8*)(Wfrag +                                  \
                    ((size_t)((wave * 6 + ni) * 24 + (KC)) * 64 + lane) * 8); \
    }
#define MFMA24(AF, B, ACX, ACY)                                               \
    {                                                                         \
        _Pragma("unroll")                                                     \
        for (int mi = 0; mi < 2; ++mi)                                        \
            _Pragma("unroll")                                                 \
            for (int ni = 0; ni < 6; ++ni) {                                  \
                ACX[mi][ni] = __builtin_amdgcn_mfma_f32_16x16x32_bf16(        \
                    AF[0][mi], B[ni], ACX[mi][ni], 0, 0, 0);                  \
                ACY[mi][ni] = __builtin_amdgcn_mfma_f32_16x16x32_bf16(        \
                    AF[1][mi], B[ni], ACY[mi][ni], 0, 0, 0);                  \
            }                                                                 \
    }
    // issue the 4 contiguous-float4 loads of step KN into set P
#define ISSUE(P, KN)                                                          \
    {                                                                         \
        const int nb_ = ((KN) >> 2) * 50176 + ((KN) & 3) * 896;               \
        P[0] = *(const float4*)(srow + nb_);                                  \
        P[1] = *(const float4*)(srow + nb_ + 4);                              \
        P[2] = *(const float4*)(srow + nb_ + 448);                            \
        P[3] = *(const float4*)(srow + nb_ + 452);                            \
    }
    // retire set P (vmcnt wait, counted by compiler) -> pack -> LDS buf
#define RETIRE(P, BUF)                                                        \
    {                                                                         \
        uint4 p0, p1;                                                         \
        p0.x = bfpack(P[0].x, P[0].y); p0.y = bfpack(P[0].z, P[0].w);         \
        p0.z = bfpack(P[1].x, P[1].y); p0.w = bfpack(P[1].z, P[1].w);         \
        p1.x = bfpack(P[2].x, P[2].y); p1.y = bfpack(P[2].z, P[2].w);         \
        p1.z = bfpack(P[3].x, P[3].y); p1.w = bfpack(P[3].z, P[3].w);         \
        *(uint4*)&As[BUF][aoff0] = p0;                                        \
        *(uint4*)&As[BUF][aoff1] = p1;                                        \
    }

    float4 pf[3][4];

    // ---- prologue: direct-stage step 0; issue steps 1,2 into pf[1], pf[2]
    if (sact) {
        float4 d0[4];
        ISSUE(d0, 0)
        RETIRE(d0, 0)
        ISSUE(pf[1], 1)
        ISSUE(pf[2], 2)
    }
    short8 b0[6], b1[6], bn[6];
    LOADB(b0, 0)
    __syncthreads();

#pragma unroll 6
    for (int kk = 0; kk < 12; ++kk) {
        const int cur = kk & 1;
        // deep prefetch: issue step kk+3 into the set freed last iter
        if (sact && (kk + 3 < 12)) ISSUE(pf[kk % 3], kk + 3)
        LOADB(b1, kk * 2 + 1)                 // ks=1 B-frags (hidden by ks0 MFMAs)
        short8 af[2][2];
#pragma unroll
        for (int t = 0; t < 2; ++t)
#pragma unroll
            for (int mi = 0; mi < 2; ++mi)
                af[t][mi] = *(const short8*)&As[cur][ob0 + ard[t][mi]];
        MFMA24(af, b0, accx, accy)
        const int kn2 = (kk < 11) ? (kk + 1) * 2 : 0;
        LOADB(bn, kn2)                        // next step ks=0 (hidden by ks1)
#pragma unroll
        for (int t = 0; t < 2; ++t)
#pragma unroll
            for (int mi = 0; mi < 2; ++mi)
                af[t][mi] = *(const short8*)&As[cur][ob1 + ard[t][mi]];
        MFMA24(af, b1, accx, accy)
        // retire step kk+1 (issued 2 iters ago) after the MFMAs
        if (sact && (kk < 11)) RETIRE(pf[(kk + 1) % 3], cur ^ 1)
#pragma unroll
        for (int ni = 0; ni < 6; ++ni) b0[ni] = bn[ni];
        __syncthreads();
    }
#undef LOADB
#undef MFMA24
#undef ISSUE
#undef RETIRE

    // ---- epilogue: D col = wave*96 + ni*16 + lm; row = mi*16 + lq*4 + r
#pragma unroll
    for (int ni = 0; ni < 6; ++ni) {
        const float bv = bias[wave * 96 + ni * 16 + lm];
#pragma unroll
        for (int mi = 0; mi < 2; ++mi)
#pragma unroll
            for (int r = 0; r < 4; ++r) {
                accx[mi][ni][r] += bv;
                accy[mi][ni][r] += bv;
            }
    }

    float mx[2][4], my_[2][4];
#pragma unroll
    for (int mi = 0; mi < 2; ++mi)
#pragma unroll
        for (int r = 0; r < 4; ++r) {
            float a = accx[mi][0][r], bb = accy[mi][0][r];
#pragma unroll
            for (int ni = 1; ni < 6; ++ni) {
                a  = fmaxf(a,  accx[mi][ni][r]);
                bb = fmaxf(bb, accy[mi][ni][r]);
            }
            mx[mi][r] = a; my_[mi][r] = bb;
        }
#pragma unroll
    for (int off = 1; off < 16; off <<= 1)
#pragma unroll
        for (int mi = 0; mi < 2; ++mi)
#pragma unroll
            for (int r = 0; r < 4; ++r) {
                mx[mi][r]  = fmaxf(mx[mi][r],  __shfl_xor(mx[mi][r],  off));
                my_[mi][r] = fmaxf(my_[mi][r], __shfl_xor(my_[mi][r], off));
            }
    if (lm == 0)
#pragma unroll
        for (int mi = 0; mi < 2; ++mi)
#pragma unroll
            for (int r = 0; r < 4; ++r) {
                Smx[wave][mi * 16 + lq * 4 + r] = mx[mi][r];
                Smy[wave][mi * 16 + lq * 4 + r] = my_[mi][r];
            }
    __syncthreads();
#pragma unroll
    for (int mi = 0; mi < 2; ++mi)
#pragma unroll
        for (int r = 0; r < 4; ++r) {
            const int row = mi * 16 + lq * 4 + r;
            mx[mi][r]  = fmaxf(fmaxf(Smx[0][row], Smx[1][row]),
                               fmaxf(Smx[2][row], Smx[3][row]));
            my_[mi][r] = fmaxf(fmaxf(Smy[0][row], Smy[1][row]),
                               fmaxf(Smy[2][row], Smy[3][row]));
        }

    float sx[2][4], sy[2][4];
#pragma unroll
    for (int mi = 0; mi < 2; ++mi)
#pragma unroll
        for (int r = 0; r < 4; ++r) {
            float a = 0.f, bb = 0.f;
#pragma unroll
            for (int ni = 0; ni < 6; ++ni) {
                a  += __expf(accx[mi][ni][r] - mx[mi][r]);
                bb += __expf(accy[mi][ni][r] - my_[mi][r]);
            }
            sx[mi][r] = a; sy[mi][r] = bb;
        }
#pragma unroll
    for (int off = 1; off < 16; off <<= 1)
#pragma unroll
        for (int mi = 0; mi < 2; ++mi)
#pragma unroll
            for (int r = 0; r < 4; ++r) {
                sx[mi][r] += __shfl_xor(sx[mi][r], off);
                sy[mi][r] += __shfl_xor(sy[mi][r], off);
            }
    if (lm == 0)
#pragma unroll
        for (int mi = 0; mi < 2; ++mi)
#pragma unroll
            for (int r = 0; r < 4; ++r) {
                Ssx[wave][mi * 16 + lq * 4 + r] = sx[mi][r];
                Ssy[wave][mi * 16 + lq * 4 + r] = sy[mi][r];
            }
    __syncthreads();
    float shx[2][4], invy[2][4];
#pragma unroll
    for (int mi = 0; mi < 2; ++mi)
#pragma unroll
        for (int r = 0; r < 4; ++r) {
            const int row = mi * 16 + lq * 4 + r;
            const float ssx = Ssx[0][row] + Ssx[1][row] + Ssx[2][row] + Ssx[3][row];
            const float ssy = Ssy[0][row] + Ssy[1][row] + Ssy[2][row] + Ssy[3][row];
            shx[mi][r]  = mx[mi][r] + __logf(ssx);   // logp shift
            invy[mi][r] = 1.f / ssy;                 // q scale
        }

    // ---- T partial (fp32) + packed bf16x2 (logp,q) stores (rows m < 28)
    float T = 0.f;
#pragma unroll
    for (int mi = 0; mi < 2; ++mi)
#pragma unroll
        for (int r = 0; r < 4; ++r) {
            const int m = mi * 16 + lq * 4 + r;
            if (m < 28) {
                const int img = (m >= 14) ? 1 : 0;
                const int pj  = m - img * 14;
                const size_t lb = ((size_t)(pi * 14 + pj) * 64 + ig * 2 + img) * 384
                                  + wave * 96 + lm;
                const float sh  = shx[mi][r];
                const float mm  = my_[mi][r];
                const float inv = invy[mi][r];
#pragma unroll
                for (int ni = 0; ni < 6; ++ni) {
                    const float lp = accx[mi][ni][r] - sh;
                    const float qv = __expf(accy[mi][ni][r] - mm) * inv;
                    T += lp * qv;
                    Zg[lb + ni * 16] = cvtpk(lp, qv);   // bf16 lp | bf16 qv <<16
                }
            }
        }
#pragma unroll
    for (int off = 32; off > 0; off >>= 1) T += __shfl_xor(T, off);
    if (lane == 0) sT[wave] = T;
    __syncthreads();
    if (tid == 0) atomicAdd(&scal[0], sT[0] + sT[1] + sT[2] + sT[3]);
}

// ---------------- fin: per-position L/Q col sums -> S; final scalar ---------
// grid 196 (one block per position; Zg[p] is one contiguous 98 KB stream),
// block 768: (img-half h, col c).
__global__ __launch_bounds__(768) void fin(const unsigned* __restrict__ Zg,
                                           float* __restrict__ scal,
                                           float* __restrict__ out) {
    const int p = blockIdx.x;
    const int t = threadIdx.x;
    const int h = t / 384;                     // img half
    const int c = t - h * 384;                 // 0..383
    float L = 0.f, Q = 0.f;
#pragma unroll 4
    for (int i = 0; i < 32; ++i) {
        const unsigned u = Zg[((size_t)p * 64 + h * 32 + i) * 384 + c];
        L += bf2f(u << 16);
        Q += bf2f(u & 0xffff0000u);
    }
    __shared__ float LL[384], QQ[384];
    if (h == 0) { LL[c] = L; QQ[c] = Q; }
    __syncthreads();
    float s = 0.f;
    if (h == 1) s = (LL[c] + L) * (QQ[c] + Q);
#pragma unroll
    for (int off = 32; off > 0; off >>= 1) s += __shfl_xor(s, off);
    __shared__ float sw[12];
    if ((t & 63) == 0) sw[t >> 6] = s;
    __syncthreads();
    if (t == 0) {
        float Sp = 0.f;
#pragma unroll
        for (int w = 0; w < 12; ++w) Sp += sw[w];
        atomicAdd(&scal[1], Sp);
        __threadfence();
        const int old = atomicAdd((int*)&scal[3], 1);
        if (old == POS - 1) {
            const float T = atomicAdd(&scal[0], 0.f);   // coherent read-back
            const float S = atomicAdd(&scal[1], 0.f);
            out[0] = 63.f * T / (S - T);
        }
    }
}

extern "C" void kernel_launch(void* const* d_in, const int* in_sizes, int n_in,
                              void* d_out, int out_size, void* d_ws, size_t ws_size,
                              hipStream_t stream) {
    const float* x = (const float*)d_in[0];   // (64,3,224,224)
    const float* y = (const float*)d_in[1];   // (64,3,224,224)
    const float* W = (const float*)d_in[2];   // (384,768)
    const float* b = (const float*)d_in[3];   // (384,)
    float* out = (float*)d_out;

    char* ws = (char*)d_ws;
    float*    scal  = (float*)ws;                      // 64 B (pad to 1 KB)
    ushort_t* Wfrag = (ushort_t*)(ws + 1024);          // 589,824 B
    unsigned* Zg    = (unsigned*)(ws + 590848);        // 19,267,584 B

    prep<<<144, 256, 0, stream>>>(W, Wfrag, scal);
    pef<<<448, 256, 0, stream>>>(x, y, Wfrag, b, scal, Zg);
    fin<<<196, 768, 0, stream>>>(Zg, scal, out);
}